// Round 2
// baseline (365.064 us; speedup 1.0000x reference)
//
#include <hip/hip_runtime.h>

#define NBATCH 32
#define NFEAT 48
#define C1c 6
#define LRC 42
#define HH 128
#define WW 128
#define HWSZ 16384
#define NP 81
#define NQ 64

// workspace layout (in floats)
#define OFF_PM   0                      // 81*64 = 5184
#define OFF_GAP  5184                   // 32*42 = 1344
#define OFF_K    6528                   // 64*64 = 4096
#define OFF_ATTN 10624                  // 1344
#define OFF_HR   11968                  // 32*6*16384 = 3145728

// ---------------- K1: per-pixel softmax over 81 ch, binned into pm_sum[81][64] ----------------
// Each thread owns a fixed (x, y&7, b, quarter): all its pixels land in the SAME q-bin.
// Private register accumulation; single cross-lane reduce at the end.
__global__ __launch_bounds__(256, 2) void k_softmax_pm(const float* __restrict__ logits,
                                                       float* __restrict__ pm_sum) {
    int bid = blockIdx.x;           // 512 = b(32) * ygp(4) * quarter(4)
    int b   = bid >> 4;
    int ygp = (bid >> 2) & 3;
    int qq  = bid & 3;
    int tid = threadIdx.x;
    int x   = tid & 127;
    int yg  = ygp * 2 + (tid >> 7);

    float acc[NP];
#pragma unroll
    for (int p = 0; p < NP; ++p) acc[p] = 0.f;

    for (int k = 0; k < 4; ++k) {
        int y = yg + 8 * (qq * 4 + k);
        const float* base = logits + (size_t)b * NP * HWSZ + (y << 7) + x;
        float ev[NP];
        float s = 0.f;
#pragma unroll
        for (int p = 0; p < NP; ++p) { ev[p] = __expf(base[(size_t)p * HWSZ]); s += ev[p]; }
        float inv = 1.f / s;
#pragma unroll
        for (int p = 0; p < NP; ++p) acc[p] += ev[p] * inv;
    }
    int lane = tid & 63;
#pragma unroll
    for (int p = 0; p < NP; ++p) {
        float e = acc[p];
        e += __shfl_xor(e, 8);
        e += __shfl_xor(e, 16);
        e += __shfl_xor(e, 32);
        if (lane < 8) atomicAdd(&pm_sum[p * NQ + (yg << 3) + lane], e);
    }
}

// ---------------- K2: gap_sum[b][c] = sum over HxW of feat[b, 6+c] ----------------
__global__ __launch_bounds__(256) void k_gap(const float* __restrict__ feat,
                                             float* __restrict__ gap) {
    int bid = blockIdx.x;
    int b = bid / LRC, c = bid % LRC;
    const float4* p = (const float4*)(feat + ((size_t)b * NFEAT + C1c + c) * HWSZ);
    float s = 0.f;
    for (int i = threadIdx.x; i < HWSZ / 4; i += 256) {
        float4 v = p[i];
        s += (v.x + v.y) + (v.z + v.w);
    }
    s += __shfl_xor(s, 1);  s += __shfl_xor(s, 2);  s += __shfl_xor(s, 4);
    s += __shfl_xor(s, 8);  s += __shfl_xor(s, 16); s += __shfl_xor(s, 32);
    __shared__ float w4[4];
    if ((threadIdx.x & 63) == 0) w4[threadIdx.x >> 6] = s;
    __syncthreads();
    if (threadIdx.x == 0) gap[bid] = w4[0] + w4[1] + w4[2] + w4[3];
}

// ---------------- K3: build K (64x64) and attn (32x42) ----------------
__global__ __launch_bounds__(256) void k_small(const float* __restrict__ pm_sum,
                                               const float* __restrict__ gap_sum,
                                               const float* __restrict__ sigx,
                                               const float* __restrict__ sigy,
                                               const float* __restrict__ opac,
                                               const float* __restrict__ rho,
                                               const float* __restrict__ w_v2,
                                               float* __restrict__ Kmat,
                                               float* __restrict__ attn) {
    int tid = threadIdx.x;
    if (tid < 64) {
        int q = tid;
        float wsx = 0.f, wsy = 0.f, wop = 0.f, wr = 0.f;
        for (int p = 0; p < NP; ++p) {
            float pv = pm_sum[p * NQ + q] * (1.f / 8192.f);
            wsx += sigx[p] * pv;
            wsy += sigy[p] * pv;
            wop += opac[p] * pv;
            wr  += rho[p]  * pv;
        }
        float a = wsx * wsx, d = wsy * wsy, bc = wr * wsx * wsy;
        float det = a * d - bc * bc;
        float i00 = d / det, i01 = -bc / det, i11 = a / det;
        int iq = q >> 3, jq = q & 7;
        for (int h = 0; h < 8; ++h)
            for (int w = 0; w < 8; ++w) {
                int ki = h - iq + 2, kj = w - jq + 2;
                float val = 0.f;
                if (ki >= 0 && ki < 5 && kj >= 0 && kj < 5) {
                    float xx = -5.f + 2.5f * ki, yy = -5.f + 2.5f * kj;
                    val = wop * __expf(-0.5f * (i00 * xx * xx + 2.f * i01 * xx * yy + i11 * yy * yy));
                }
                Kmat[(q << 6) + (h << 3) + w] = val;
            }
    }
    for (int i = tid; i < NBATCH * LRC; i += 256) {
        int b = i / LRC, co = i % LRC;
        float s = 0.f;
        for (int ci = 0; ci < LRC; ++ci) s += w_v2[co * LRC + ci] * gap_sum[b * LRC + ci];
        s *= (1.f / 16384.f);
        attn[i] = 1.f / (1.f + __expf(-s));
    }
}

// ---------------- K4: hr = (colors @ K) * V1, materialized to ws ----------------
__global__ __launch_bounds__(256) void k_hr(const float* __restrict__ feat,
                                            const float* __restrict__ V,
                                            const float* __restrict__ Kmat,
                                            float* __restrict__ hr) {
    __shared__ __align__(16) float lds[16384];  // [0..4095]=K[q][pos], rest = feat strip [6][16][128]
    float* lK = lds;
    float* lF = lds + 4096;
    int bid = blockIdx.x;
    int b = bid >> 3;
    int y0 = (bid & 7) << 4;
    int tid = threadIdx.x;
    for (int i = tid; i < 4096; i += 256) lK[i] = Kmat[i];
    for (int i = tid; i < 12288; i += 256) {
        int c = i >> 11, rem = i & 2047;
        lF[i] = feat[(((size_t)b * NFEAT + c) << 14) + (((size_t)y0 + (rem >> 7)) << 7) + (rem & 127)];
    }
    __syncthreads();
    int tile = tid >> 3, hrow = tid & 7;
    int tr = tile >> 4, tx = tile & 15;
    float acc[6][8];
#pragma unroll
    for (int c = 0; c < 6; ++c)
#pragma unroll
        for (int j = 0; j < 8; ++j) acc[c][j] = 0.f;
    int fbase = (tr << 3) * 128 + (tx << 3);
    for (int q = 0; q < 64; ++q) {
        int iq = q >> 3, jq = q & 7;
        const float4 k0 = *(const float4*)&lK[(q << 6) + (hrow << 3)];
        const float4 k1 = *(const float4*)&lK[(q << 6) + (hrow << 3) + 4];
#pragma unroll
        for (int c = 0; c < 6; ++c) {
            float col = lF[(c << 11) + fbase + (iq << 7) + jq];
            acc[c][0] += col * k0.x; acc[c][1] += col * k0.y;
            acc[c][2] += col * k0.z; acc[c][3] += col * k0.w;
            acc[c][4] += col * k1.x; acc[c][5] += col * k1.y;
            acc[c][6] += col * k1.z; acc[c][7] += col * k1.w;
        }
    }
    int y = y0 + (tr << 3) + hrow;
#pragma unroll
    for (int c = 0; c < 6; ++c) {
        const float4* vp = (const float4*)(V + (((size_t)b * NFEAT + c) << 14) + ((size_t)y << 7) + (tx << 3));
        float4 v0 = vp[0], v1 = vp[1];
        float4 r0, r1;
        r0.x = acc[c][0] * v0.x; r0.y = acc[c][1] * v0.y; r0.z = acc[c][2] * v0.z; r0.w = acc[c][3] * v0.w;
        r1.x = acc[c][4] * v1.x; r1.y = acc[c][5] * v1.y; r1.z = acc[c][6] * v1.z; r1.w = acc[c][7] * v1.w;
        float4* op = (float4*)(hr + (((size_t)b * C1c + c) << 14) + ((size_t)y << 7) + (tx << 3));
        op[0] = r0; op[1] = r1;
    }
}

// ---------------- K5: fused conv3x3(out_feat) + conv1x1(feat) + biases + up(ms) ----------------
// 32x32 output tile, 128 threads, 8 px/thread (2y x 4x), channels staged in chunks of 8.
// Weights/attn via uniform scalar loads; LDS row stride 36 -> conflict-free b128/b64 reads.
#define CCH 8
__global__ __launch_bounds__(128, 2) void k_conv(const float* __restrict__ feat,
                                                 const float* __restrict__ V,
                                                 const float* __restrict__ ms,
                                                 const float* __restrict__ w_fine,
                                                 const float* __restrict__ b_fine,
                                                 const float* __restrict__ w_res,
                                                 const float* __restrict__ b_res,
                                                 const float* __restrict__ hr,
                                                 const float* __restrict__ attn,
                                                 float* __restrict__ out) {
    __shared__ __align__(16) float s_in[CCH][34 * 36];   // 39168 B
    int bid = blockIdx.x;                 // 512 = b(32) * tile(16)
    int b   = bid >> 4;
    int t16 = bid & 15;
    int ty0 = (t16 >> 2) << 5;
    int tx0 = (t16 & 3) << 5;
    int tid = threadIdx.x;                // 128
    int ty  = tid >> 3;                   // 0..15
    int tx  = tid & 7;                    // 0..7
    int py  = ty0 + 2 * ty;               // rows py, py+1
    int px  = tx0 + 4 * tx;               // cols px..px+3

    float a[4][8];
#pragma unroll
    for (int o = 0; o < 4; ++o)
#pragma unroll
        for (int j = 0; j < 8; ++j) a[o][j] = 0.f;

    for (int cb = 0; cb < NFEAT; cb += CCH) {
        __syncthreads();
        // ---- stage chunk ----
        for (int cc = 0; cc < CCH; ++cc) {
            int c = cb + cc;
            if (c < C1c) {
                const float* src = hr + (((size_t)b * C1c + c) << 14);
                for (int i = tid; i < 1156; i += 128) {
                    int r = i / 34, cl = i - r * 34;
                    int sy = ty0 - 1 + r, sx = tx0 - 1 + cl;
                    float v = 0.f;
                    if (sy >= 0 && sy < HH && sx >= 0 && sx < WW) v = src[(sy << 7) + sx];
                    s_in[cc][r * 36 + cl] = v;
                }
            } else {
                float am = attn[b * LRC + (c - C1c)];
                const float* fsrc = feat + (((size_t)b * NFEAT + c) << 14);
                const float* vsrc = V    + (((size_t)b * NFEAT + c) << 14);
                for (int i = tid; i < 1156; i += 128) {
                    int r = i / 34, cl = i - r * 34;
                    int sy = ty0 - 1 + r, sx = tx0 - 1 + cl;
                    float v = 0.f;
                    if (sy >= 0 && sy < HH && sx >= 0 && sx < WW) {
                        int g = (sy << 7) + sx;
                        v = fsrc[g] * am * vsrc[g];
                    }
                    s_in[cc][r * 36 + cl] = v;
                }
            }
        }
        __syncthreads();
        // ---- compute chunk ----
        for (int cc = 0; cc < CCH; ++cc) {
            int c = cb + cc;
            float win[4][6];
#pragma unroll
            for (int dy = 0; dy < 4; ++dy) {
                const float* rp = &s_in[cc][(2 * ty + dy) * 36 + 4 * tx];
                float4 w4 = *(const float4*)rp;
                float2 w2 = *(const float2*)(rp + 4);
                win[dy][0] = w4.x; win[dy][1] = w4.y; win[dy][2] = w4.z;
                win[dy][3] = w4.w; win[dy][4] = w2.x; win[dy][5] = w2.y;
            }
            const float* fc = feat + (((size_t)b * NFEAT + c) << 14);
            float4 f0 = *(const float4*)&fc[(py << 7) + px];
            float4 f1 = *(const float4*)&fc[((py + 1) << 7) + px];
            float fcv[8] = { f0.x, f0.y, f0.z, f0.w, f1.x, f1.y, f1.z, f1.w };
#pragma unroll
            for (int o = 0; o < 4; ++o) {
                const float* wf = w_fine + o * 432 + c * 9;   // uniform -> s_load
                float w00 = wf[0], w01 = wf[1], w02 = wf[2];
                float w10 = wf[3], w11 = wf[4], w12 = wf[5];
                float w20 = wf[6], w21 = wf[7], w22 = wf[8];
                float wr  = w_res[o * NFEAT + c];
#pragma unroll
                for (int yy = 0; yy < 2; ++yy)
#pragma unroll
                    for (int xx = 0; xx < 4; ++xx) {
                        float s = w00 * win[yy][xx]     + w01 * win[yy][xx + 1]     + w02 * win[yy][xx + 2]
                                + w10 * win[yy + 1][xx] + w11 * win[yy + 1][xx + 1] + w12 * win[yy + 1][xx + 2]
                                + w20 * win[yy + 2][xx] + w21 * win[yy + 2][xx + 1] + w22 * win[yy + 2][xx + 2];
                        a[o][yy * 4 + xx] += s + wr * fcv[yy * 4 + xx];
                    }
            }
        }
    }
    // ---- epilogue: biases + bilinear upsample of ms + store ----
#pragma unroll
    for (int o = 0; o < 4; ++o) {
        const float* mb = ms + ((size_t)(b * 4 + o) << 10);
        float addc = b_fine[o] + b_res[o];
#pragma unroll
        for (int yy = 0; yy < 2; ++yy) {
            int gy = py + yy;
            float syf = (gy + 0.5f) * 0.25f - 0.5f;
            int y0i = (int)floorf(syf); float fy = syf - (float)y0i;
            int y0c = min(31, max(0, y0i)), y1c = min(31, max(0, y0i + 1));
            float res[4];
#pragma unroll
            for (int xx = 0; xx < 4; ++xx) {
                int gx = px + xx;
                float sxf = (gx + 0.5f) * 0.25f - 0.5f;
                int x0i = (int)floorf(sxf); float fx = sxf - (float)x0i;
                int x0c = min(31, max(0, x0i)), x1c = min(31, max(0, x0i + 1));
                float m00 = mb[(y0c << 5) + x0c], m01 = mb[(y0c << 5) + x1c];
                float m10 = mb[(y1c << 5) + x0c], m11 = mb[(y1c << 5) + x1c];
                float up = (m00 * (1.f - fx) + m01 * fx) * (1.f - fy)
                         + (m10 * (1.f - fx) + m11 * fx) * fy;
                res[xx] = a[o][yy * 4 + xx] + addc + up;
            }
            *(float4*)&out[((size_t)(b * 4 + o) << 14) + (gy << 7) + px] =
                make_float4(res[0], res[1], res[2], res[3]);
        }
    }
}

extern "C" void kernel_launch(void* const* d_in, const int* in_sizes, int n_in,
                              void* d_out, int out_size, void* d_ws, size_t ws_size,
                              hipStream_t stream) {
    (void)in_sizes; (void)n_in; (void)out_size; (void)ws_size;
    const float* ms     = (const float*)d_in[0];
    const float* feat   = (const float*)d_in[1];
    const float* V      = (const float*)d_in[2];
    const float* logits = (const float*)d_in[3];
    const float* sigx   = (const float*)d_in[4];
    const float* sigy   = (const float*)d_in[5];
    const float* opac   = (const float*)d_in[6];
    const float* rho    = (const float*)d_in[7];
    const float* w_v2   = (const float*)d_in[8];
    const float* w_fine = (const float*)d_in[9];
    const float* b_fine = (const float*)d_in[10];
    const float* w_res  = (const float*)d_in[11];
    const float* b_res  = (const float*)d_in[12];
    float* ws  = (float*)d_ws;
    float* out = (float*)d_out;

    hipMemsetAsync(ws + OFF_PM, 0, (size_t)NP * NQ * sizeof(float), stream);
    k_softmax_pm<<<512, 256, 0, stream>>>(logits, ws + OFF_PM);
    k_gap<<<NBATCH * LRC, 256, 0, stream>>>(feat, ws + OFF_GAP);
    k_small<<<1, 256, 0, stream>>>(ws + OFF_PM, ws + OFF_GAP, sigx, sigy, opac, rho, w_v2,
                                   ws + OFF_K, ws + OFF_ATTN);
    k_hr<<<256, 256, 0, stream>>>(feat, V, ws + OFF_K, ws + OFF_HR);
    k_conv<<<512, 128, 0, stream>>>(feat, V, ms, w_fine, b_fine, w_res, b_res,
                                    ws + OFF_HR, ws + OFF_ATTN, out);
}

// Round 3
// 220.914 us; speedup vs baseline: 1.6525x; 1.6525x over previous
//
#include <hip/hip_runtime.h>

#define NBATCH 32
#define NFEAT 48
#define C1c 6
#define LRC 42
#define HH 128
#define WW 128
#define HWSZ 16384
#define NP 81
#define NQ 64

// workspace layout (in floats)
#define OFF_PM   0                      // 81*64 = 5184
#define OFF_GAP  5184                   // 32*42 = 1344
#define OFF_K    6528                   // 64*64 = 4096
#define OFF_ATTN 10624                  // 1344
#define OFF_WB   11968                  // 48*48 = 2304 rearranged weights
#define OFF_HR   14272                  // 32*6*16384 = 3145728

// ---------------- K1: per-pixel softmax over 81 ch, binned into pm_sum[81][64] ----------------
__global__ __launch_bounds__(256, 2) void k_softmax_pm(const float* __restrict__ logits,
                                                       float* __restrict__ pm_sum) {
    int bid = blockIdx.x;           // 512 = b(32) * ygp(4) * quarter(4)
    int b   = bid >> 4;
    int ygp = (bid >> 2) & 3;
    int qq  = bid & 3;
    int tid = threadIdx.x;
    int x   = tid & 127;
    int yg  = ygp * 2 + (tid >> 7);

    float acc[NP];
#pragma unroll
    for (int p = 0; p < NP; ++p) acc[p] = 0.f;

    for (int k = 0; k < 4; ++k) {
        int y = yg + 8 * (qq * 4 + k);
        const float* base = logits + (size_t)b * NP * HWSZ + (y << 7) + x;
        float ev[NP];
        float s = 0.f;
#pragma unroll
        for (int p = 0; p < NP; ++p) { ev[p] = __expf(base[(size_t)p * HWSZ]); s += ev[p]; }
        float inv = 1.f / s;
#pragma unroll
        for (int p = 0; p < NP; ++p) acc[p] += ev[p] * inv;
    }
    int lane = tid & 63;
#pragma unroll
    for (int p = 0; p < NP; ++p) {
        float e = acc[p];
        e += __shfl_xor(e, 8);
        e += __shfl_xor(e, 16);
        e += __shfl_xor(e, 32);
        if (lane < 8) atomicAdd(&pm_sum[p * NQ + (yg << 3) + lane], e);
    }
}

// ---------------- K2: gap_sum[b][c] = sum over HxW of feat[b, 6+c] ----------------
__global__ __launch_bounds__(256) void k_gap(const float* __restrict__ feat,
                                             float* __restrict__ gap) {
    int bid = blockIdx.x;
    int b = bid / LRC, c = bid % LRC;
    const float4* p = (const float4*)(feat + ((size_t)b * NFEAT + C1c + c) * HWSZ);
    float s = 0.f;
    for (int i = threadIdx.x; i < HWSZ / 4; i += 256) {
        float4 v = p[i];
        s += (v.x + v.y) + (v.z + v.w);
    }
    s += __shfl_xor(s, 1);  s += __shfl_xor(s, 2);  s += __shfl_xor(s, 4);
    s += __shfl_xor(s, 8);  s += __shfl_xor(s, 16); s += __shfl_xor(s, 32);
    __shared__ float w4[4];
    if ((threadIdx.x & 63) == 0) w4[threadIdx.x >> 6] = s;
    __syncthreads();
    if (threadIdx.x == 0) gap[bid] = w4[0] + w4[1] + w4[2] + w4[3];
}

// ---------------- K3: build K (64x64), attn (32x42), and rearranged weights wbuf[48][48] ----------------
__global__ __launch_bounds__(256) void k_small(const float* __restrict__ pm_sum,
                                               const float* __restrict__ gap_sum,
                                               const float* __restrict__ sigx,
                                               const float* __restrict__ sigy,
                                               const float* __restrict__ opac,
                                               const float* __restrict__ rho,
                                               const float* __restrict__ w_v2,
                                               const float* __restrict__ w_fine,
                                               const float* __restrict__ w_res,
                                               float* __restrict__ Kmat,
                                               float* __restrict__ attn,
                                               float* __restrict__ wbuf) {
    int tid = threadIdx.x;
    if (tid < 64) {
        int q = tid;
        float wsx = 0.f, wsy = 0.f, wop = 0.f, wr = 0.f;
        for (int p = 0; p < NP; ++p) {
            float pv = pm_sum[p * NQ + q] * (1.f / 8192.f);
            wsx += sigx[p] * pv;
            wsy += sigy[p] * pv;
            wop += opac[p] * pv;
            wr  += rho[p]  * pv;
        }
        float a = wsx * wsx, d = wsy * wsy, bc = wr * wsx * wsy;
        float det = a * d - bc * bc;
        float i00 = d / det, i01 = -bc / det, i11 = a / det;
        int iq = q >> 3, jq = q & 7;
        for (int h = 0; h < 8; ++h)
            for (int w = 0; w < 8; ++w) {
                int ki = h - iq + 2, kj = w - jq + 2;
                float val = 0.f;
                if (ki >= 0 && ki < 5 && kj >= 0 && kj < 5) {
                    float xx = -5.f + 2.5f * ki, yy = -5.f + 2.5f * kj;
                    val = wop * __expf(-0.5f * (i00 * xx * xx + 2.f * i01 * xx * yy + i11 * yy * yy));
                }
                Kmat[(q << 6) + (h << 3) + w] = val;
            }
    }
    for (int i = tid; i < NBATCH * LRC; i += 256) {
        int b = i / LRC, co = i % LRC;
        float s = 0.f;
        for (int ci = 0; ci < LRC; ++ci) s += w_v2[co * LRC + ci] * gap_sum[b * LRC + ci];
        s *= (1.f / 16384.f);
        attn[i] = 1.f / (1.f + __expf(-s));
    }
    // wbuf[c*48 + o*9 + t] = w_fine[o][c][t];  wbuf[c*48 + 36 + o] = w_res[o][c]
    for (int i = tid; i < NFEAT * 48; i += 256) {
        int c = i / 48, j = i - c * 48;
        float v = 0.f;
        if (j < 36) v = w_fine[(j / 9) * (NFEAT * 9) + c * 9 + (j % 9)];
        else if (j < 40) v = w_res[(j - 36) * NFEAT + c];
        wbuf[i] = v;
    }
}

// ---------------- K4: hr = (colors @ K) * V1, materialized to ws ----------------
__global__ __launch_bounds__(256) void k_hr(const float* __restrict__ feat,
                                            const float* __restrict__ V,
                                            const float* __restrict__ Kmat,
                                            float* __restrict__ hr) {
    __shared__ __align__(16) float lds[16384];  // [0..4095]=K[q][pos], rest = feat strip [6][16][128]
    float* lK = lds;
    float* lF = lds + 4096;
    int bid = blockIdx.x;
    int b = bid >> 3;
    int y0 = (bid & 7) << 4;
    int tid = threadIdx.x;
    for (int i = tid; i < 4096; i += 256) lK[i] = Kmat[i];
    for (int i = tid; i < 12288; i += 256) {
        int c = i >> 11, rem = i & 2047;
        lF[i] = feat[(((size_t)b * NFEAT + c) << 14) + (((size_t)y0 + (rem >> 7)) << 7) + (rem & 127)];
    }
    __syncthreads();
    int tile = tid >> 3, hrow = tid & 7;
    int tr = tile >> 4, tx = tile & 15;
    float acc[6][8];
#pragma unroll
    for (int c = 0; c < 6; ++c)
#pragma unroll
        for (int j = 0; j < 8; ++j) acc[c][j] = 0.f;
    int fbase = (tr << 3) * 128 + (tx << 3);
    for (int q = 0; q < 64; ++q) {
        int iq = q >> 3, jq = q & 7;
        const float4 k0 = *(const float4*)&lK[(q << 6) + (hrow << 3)];
        const float4 k1 = *(const float4*)&lK[(q << 6) + (hrow << 3) + 4];
#pragma unroll
        for (int c = 0; c < 6; ++c) {
            float col = lF[(c << 11) + fbase + (iq << 7) + jq];
            acc[c][0] += col * k0.x; acc[c][1] += col * k0.y;
            acc[c][2] += col * k0.z; acc[c][3] += col * k0.w;
            acc[c][4] += col * k1.x; acc[c][5] += col * k1.y;
            acc[c][6] += col * k1.z; acc[c][7] += col * k1.w;
        }
    }
    int y = y0 + (tr << 3) + hrow;
#pragma unroll
    for (int c = 0; c < 6; ++c) {
        const float4* vp = (const float4*)(V + (((size_t)b * NFEAT + c) << 14) + ((size_t)y << 7) + (tx << 3));
        float4 v0 = vp[0], v1 = vp[1];
        float4 r0, r1;
        r0.x = acc[c][0] * v0.x; r0.y = acc[c][1] * v0.y; r0.z = acc[c][2] * v0.z; r0.w = acc[c][3] * v0.w;
        r1.x = acc[c][4] * v1.x; r1.y = acc[c][5] * v1.y; r1.z = acc[c][6] * v1.z; r1.w = acc[c][7] * v1.w;
        float4* op = (float4*)(hr + (((size_t)b * C1c + c) << 14) + ((size_t)y << 7) + (tx << 3));
        op[0] = r0; op[1] = r1;
    }
}

// ---------------- K5: fused conv3x3 + conv1x1 + biases + up(ms) ----------------
// 16x32 tile, 256 threads (4 waves), 2 px/thread (2 rows x 1 col), CCH=8 chunks.
// 1024 blocks -> 4 blocks/CU -> 16 waves/CU. Weights via contiguous s_load from wbuf.
#define CCH 8
__global__ __launch_bounds__(256, 4) void k_conv(const float* __restrict__ feat,
                                                 const float* __restrict__ V,
                                                 const float* __restrict__ ms,
                                                 const float* __restrict__ wbuf,
                                                 const float* __restrict__ b_fine,
                                                 const float* __restrict__ b_res,
                                                 const float* __restrict__ hr,
                                                 const float* __restrict__ attn,
                                                 float* __restrict__ out) {
    __shared__ __align__(16) float s_in[CCH][18 * 36];   // 20736 B
    int bid = blockIdx.x;                 // 1024 = b(32) * tile(32)
    int b   = bid >> 5;
    int t32 = bid & 31;
    int ty0 = (t32 >> 2) << 4;            // 8 row-tiles of 16
    int tx0 = (t32 & 3) << 5;             // 4 col-tiles of 32
    int tid = threadIdx.x;
    int ty  = tid >> 5;                   // 0..7
    int lx  = tid & 31;                   // 0..31
    int py  = ty0 + 2 * ty;               // output rows py, py+1
    int gx  = tx0 + lx;

    float a[4][2];
#pragma unroll
    for (int o = 0; o < 4; ++o) { a[o][0] = 0.f; a[o][1] = 0.f; }

    for (int cb = 0; cb < NFEAT; cb += CCH) {
        __syncthreads();
        // ---- stage chunk (uniform cc, 3 strided iterations each) ----
        for (int cc = 0; cc < CCH; ++cc) {
            int c = cb + cc;
            if (c < C1c) {
                const float* src = hr + (((size_t)b * C1c + c) << 14);
                for (int i = tid; i < 612; i += 256) {
                    int r = i / 34, cl = i - r * 34;
                    int sy = ty0 - 1 + r, sx = tx0 - 1 + cl;
                    float v = 0.f;
                    if (sy >= 0 && sy < HH && sx >= 0 && sx < WW) v = src[(sy << 7) + sx];
                    s_in[cc][r * 36 + cl] = v;
                }
            } else {
                float am = attn[b * LRC + (c - C1c)];
                const float* fsrc = feat + (((size_t)b * NFEAT + c) << 14);
                const float* vsrc = V    + (((size_t)b * NFEAT + c) << 14);
                for (int i = tid; i < 612; i += 256) {
                    int r = i / 34, cl = i - r * 34;
                    int sy = ty0 - 1 + r, sx = tx0 - 1 + cl;
                    float v = 0.f;
                    if (sy >= 0 && sy < HH && sx >= 0 && sx < WW) {
                        int g = (sy << 7) + sx;
                        v = fsrc[g] * am * vsrc[g];
                    }
                    s_in[cc][r * 36 + cl] = v;
                }
            }
        }
        __syncthreads();
        // ---- compute chunk ----
        for (int cc = 0; cc < CCH; ++cc) {
            int c = cb + cc;
            const float* wc = wbuf + c * 48;          // uniform -> s_load_dwordx16
            float4 s0 = *(const float4*)&s_in[cc][(2 * ty + 0) * 36 + lx];
            float4 s1 = *(const float4*)&s_in[cc][(2 * ty + 1) * 36 + lx];
            float4 s2 = *(const float4*)&s_in[cc][(2 * ty + 2) * 36 + lx];
            float4 s3 = *(const float4*)&s_in[cc][(2 * ty + 3) * 36 + lx];
            const float* fc = feat + (((size_t)b * NFEAT + c) << 14);
            float fc0 = fc[(py << 7) + gx];
            float fc1 = fc[((py + 1) << 7) + gx];
#pragma unroll
            for (int o = 0; o < 4; ++o) {
                float w00 = wc[o * 9 + 0], w01 = wc[o * 9 + 1], w02 = wc[o * 9 + 2];
                float w10 = wc[o * 9 + 3], w11 = wc[o * 9 + 4], w12 = wc[o * 9 + 5];
                float w20 = wc[o * 9 + 6], w21 = wc[o * 9 + 7], w22 = wc[o * 9 + 8];
                float wr  = wc[36 + o];
                float r0 = w00 * s0.x + w01 * s0.y + w02 * s0.z
                         + w10 * s1.x + w11 * s1.y + w12 * s1.z
                         + w20 * s2.x + w21 * s2.y + w22 * s2.z
                         + wr * fc0;
                float r1 = w00 * s1.x + w01 * s1.y + w02 * s1.z
                         + w10 * s2.x + w11 * s2.y + w12 * s2.z
                         + w20 * s3.x + w21 * s3.y + w22 * s3.z
                         + wr * fc1;
                a[o][0] += r0;
                a[o][1] += r1;
            }
        }
    }
    // ---- epilogue: biases + bilinear upsample of ms + store ----
#pragma unroll
    for (int o = 0; o < 4; ++o) {
        const float* mb = ms + ((size_t)(b * 4 + o) << 10);
        float addc = b_fine[o] + b_res[o];
#pragma unroll
        for (int yy = 0; yy < 2; ++yy) {
            int gy = py + yy;
            float syf = (gy + 0.5f) * 0.25f - 0.5f;
            int y0i = (int)floorf(syf); float fy = syf - (float)y0i;
            int y0c = min(31, max(0, y0i)), y1c = min(31, max(0, y0i + 1));
            float sxf = (gx + 0.5f) * 0.25f - 0.5f;
            int x0i = (int)floorf(sxf); float fx = sxf - (float)x0i;
            int x0c = min(31, max(0, x0i)), x1c = min(31, max(0, x0i + 1));
            float m00 = mb[(y0c << 5) + x0c], m01 = mb[(y0c << 5) + x1c];
            float m10 = mb[(y1c << 5) + x0c], m11 = mb[(y1c << 5) + x1c];
            float up = (m00 * (1.f - fx) + m01 * fx) * (1.f - fy)
                     + (m10 * (1.f - fx) + m11 * fx) * fy;
            out[((size_t)(b * 4 + o) << 14) + (gy << 7) + gx] = a[o][yy] + addc + up;
        }
    }
}

extern "C" void kernel_launch(void* const* d_in, const int* in_sizes, int n_in,
                              void* d_out, int out_size, void* d_ws, size_t ws_size,
                              hipStream_t stream) {
    (void)in_sizes; (void)n_in; (void)out_size; (void)ws_size;
    const float* ms     = (const float*)d_in[0];
    const float* feat   = (const float*)d_in[1];
    const float* V      = (const float*)d_in[2];
    const float* logits = (const float*)d_in[3];
    const float* sigx   = (const float*)d_in[4];
    const float* sigy   = (const float*)d_in[5];
    const float* opac   = (const float*)d_in[6];
    const float* rho    = (const float*)d_in[7];
    const float* w_v2   = (const float*)d_in[8];
    const float* w_fine = (const float*)d_in[9];
    const float* b_fine = (const float*)d_in[10];
    const float* w_res  = (const float*)d_in[11];
    const float* b_res  = (const float*)d_in[12];
    float* ws  = (float*)d_ws;
    float* out = (float*)d_out;

    hipMemsetAsync(ws + OFF_PM, 0, (size_t)NP * NQ * sizeof(float), stream);
    k_softmax_pm<<<512, 256, 0, stream>>>(logits, ws + OFF_PM);
    k_gap<<<NBATCH * LRC, 256, 0, stream>>>(feat, ws + OFF_GAP);
    k_small<<<1, 256, 0, stream>>>(ws + OFF_PM, ws + OFF_GAP, sigx, sigy, opac, rho, w_v2,
                                   w_fine, w_res, ws + OFF_K, ws + OFF_ATTN, ws + OFF_WB);
    k_hr<<<256, 256, 0, stream>>>(feat, V, ws + OFF_K, ws + OFF_HR);
    k_conv<<<1024, 256, 0, stream>>>(feat, V, ms, ws + OFF_WB, b_fine, b_res,
                                     ws + OFF_HR, ws + OFF_ATTN, out);
}